// Round 1
// baseline (405.060 us; speedup 1.0000x reference)
//
#include <hip/hip_runtime.h>
#include <stdint.h>

#define IN_LEN 4096
#define NFEAT  10000

// ---------- sortable-key mapping for float order statistics ----------
__device__ __forceinline__ unsigned key_of(float f) {
  unsigned u = __float_as_uint(f);
  return (u & 0x80000000u) ? ~u : (u | 0x80000000u);
}
__device__ __forceinline__ float key_inv(unsigned k) {
  unsigned u = (k & 0x80000000u) ? (k ^ 0x80000000u) : ~k;
  return __uint_as_float(u);
}

// ---------- kernel A: per-sample quantiles of conv0 (kernel 0, d=1) ----------
// Each block = one sample. conv0 values (4088) live in registers (16/thread).
// Binary search in u32 key space for 6 order statistics simultaneously.
__global__ __launch_bounds__(256) void quant_kernel(const float* __restrict__ x,
                                                    const float* __restrict__ kern,
                                                    float* __restrict__ ws_q) {
  const int b = blockIdx.x, tid = threadIdx.x;
  __shared__ __align__(16) float xs[IN_LEN];
  __shared__ unsigned redc[6 * 4];

  const float4* xg = (const float4*)(x + (size_t)b * IN_LEN);
  float4* xs4 = (float4*)xs;
  for (int i = tid; i < IN_LEN / 4; i += 256) xs4[i] = xg[i];

  float w[9];
#pragma unroll
  for (int j = 0; j < 9; j++) w[j] = kern[j];
  __syncthreads();

  const int L = IN_LEN - 8;  // 4088 valid conv positions at d=1
  unsigned keys[16];
#pragma unroll
  for (int i = 0; i < 16; i++) {
    int t = tid + (i << 8);
    if (t < L) {
      float c = 0.f;
#pragma unroll
      for (int j = 0; j < 9; j++) c = fmaf(w[j], xs[t + j], c);
      keys[i] = key_of(c);
    } else {
      keys[i] = 0xFFFFFFFFu;  // +inf pad, sorts above all real values
    }
  }

  // order-statistic indices (0-based): floor/ceil pairs for q=.25,.5,.75 of n=4088
  const int targ[6] = {1021, 1022, 2043, 2044, 3065, 3066};
  unsigned lo[6], hi[6];
#pragma unroll
  for (int q = 0; q < 6; q++) { lo[q] = 0u; hi[q] = 0xFFFFFFFFu; }

  const int wave = tid >> 6, lane = tid & 63;
  for (int it = 0; it < 32; ++it) {
    unsigned mid[6];
    int cnt[6];
#pragma unroll
    for (int q = 0; q < 6; q++) { mid[q] = lo[q] + ((hi[q] - lo[q]) >> 1); cnt[q] = 0; }
#pragma unroll
    for (int i = 0; i < 16; i++)
#pragma unroll
      for (int q = 0; q < 6; q++) cnt[q] += (keys[i] <= mid[q]) ? 1 : 0;
#pragma unroll
    for (int q = 0; q < 6; q++) {
#pragma unroll
      for (int off = 32; off > 0; off >>= 1) cnt[q] += __shfl_down(cnt[q], off);
    }
    if (lane == 0) {
#pragma unroll
      for (int q = 0; q < 6; q++) redc[q * 4 + wave] = (unsigned)cnt[q];
    }
    __syncthreads();
#pragma unroll
    for (int q = 0; q < 6; q++) {
      unsigned tot = redc[q * 4 + 0] + redc[q * 4 + 1] + redc[q * 4 + 2] + redc[q * 4 + 3];
      if (tot >= (unsigned)(targ[q] + 1)) hi[q] = mid[q]; else lo[q] = mid[q] + 1;
    }
    __syncthreads();
  }

  if (tid == 0) {
    float v[6];
#pragma unroll
    for (int q = 0; q < 6; q++) v[q] = key_inv(lo[q]);
    // linear interpolation at positions 1021.75 / 2043.5 / 3065.25
    ws_q[b * 3 + 0] = v[0] + 0.75f * (v[1] - v[0]);
    ws_q[b * 3 + 1] = v[2] + 0.5f  * (v[3] - v[2]);
    ws_q[b * 3 + 2] = v[4] + 0.25f * (v[5] - v[4]);
  }
}

// ---------- kernel A2: deterministic mean over batch -> 3 biases ----------
__global__ __launch_bounds__(256) void bias_kernel(const float* __restrict__ ws_q,
                                                   float* __restrict__ ws_bias, int B) {
  __shared__ float red[256];
  const int tid = threadIdx.x;
  for (int q = 0; q < 3; q++) {
    float v = 0.f;
    for (int i = tid; i < B; i += 256) v += ws_q[i * 3 + q];
    red[tid] = v;
    __syncthreads();
    for (int s = 128; s > 0; s >>= 1) {
      if (tid < s) red[tid] += red[tid + s];
      __syncthreads();
    }
    if (tid == 0) ws_bias[q] = red[0] / (float)B;
    __syncthreads();
  }
}

// ---------- kernel B: features. One block per (dilation, sample). ----------
template <int D>
__device__ __forceinline__ void run_feat(float* xs, unsigned* cr,
                                         const float* __restrict__ kern,
                                         float b0, float b1, float b2,
                                         float* __restrict__ out, int K, int b) {
  const int tid = threadIdx.x;
  constexpr int L = IN_LEN - 8 * D;
  constexpr int KT = 8;  // kernel tile: amortize 9 LDS tap reads over 8 kernels
  const int wave = tid >> 6, lane = tid & 63;

  for (int k0 = 0; k0 < K; k0 += KT) {
    float w[KT][9];
#pragma unroll
    for (int kk = 0; kk < KT; kk++) {
      const float* wp = kern + (size_t)(k0 + kk) * 9;
      const bool ok = (k0 + kk) < K;
#pragma unroll
      for (int j = 0; j < 9; j++) w[kk][j] = ok ? wp[j] : 0.f;
    }
    unsigned cnt[KT][3];
#pragma unroll
    for (int kk = 0; kk < KT; kk++) { cnt[kk][0] = 0; cnt[kk][1] = 0; cnt[kk][2] = 0; }

    // main positions: i=0..14 are always fully valid (t<=3839 < L>=4048)
#pragma unroll 2
    for (int i = 0; i < 15; i++) {
      const int t = tid + (i << 8);
      float tap[9];
#pragma unroll
      for (int j = 0; j < 9; j++) tap[j] = xs[t + j * D];  // compile-time offsets -> ds_read2
#pragma unroll
      for (int kk = 0; kk < KT; kk++) {
        float c = 0.f;
#pragma unroll
        for (int j = 0; j < 9; j++) c = fmaf(w[kk][j], tap[j], c);
        cnt[kk][0] += (unsigned)__popcll(__ballot(c > b0));
        cnt[kk][1] += (unsigned)__popcll(__ballot(c > b1));
        cnt[kk][2] += (unsigned)__popcll(__ballot(c > b2));
      }
    }
    {  // peeled tail: i=15, mask t >= L
      const int t = tid + (15 << 8);
      const bool valid = t < L;
      float tap[9];
#pragma unroll
      for (int j = 0; j < 9; j++) tap[j] = xs[t + j * D];  // xs padded to 4144, safe
#pragma unroll
      for (int kk = 0; kk < KT; kk++) {
        float c = 0.f;
#pragma unroll
        for (int j = 0; j < 9; j++) c = fmaf(w[kk][j], tap[j], c);
        c = valid ? c : -3.0e38f;
        cnt[kk][0] += (unsigned)__popcll(__ballot(c > b0));
        cnt[kk][1] += (unsigned)__popcll(__ballot(c > b1));
        cnt[kk][2] += (unsigned)__popcll(__ballot(c > b2));
      }
    }

    // combine the 4 waves' counts, write features
    if (lane == 0) {
#pragma unroll
      for (int kk = 0; kk < KT; kk++) {
        cr[(kk * 3 + 0) * 4 + wave] = cnt[kk][0];
        cr[(kk * 3 + 1) * 4 + wave] = cnt[kk][1];
        cr[(kk * 3 + 2) * 4 + wave] = cnt[kk][2];
      }
    }
    __syncthreads();
    if (tid < KT * 3) {
      const int kk = tid / 3, q = tid - kk * 3;
      const int k = k0 + kk;
      if (k < K) {
        unsigned tot = cr[tid * 4 + 0] + cr[tid * 4 + 1] + cr[tid * 4 + 2] + cr[tid * 4 + 3];
        out[(size_t)b * NFEAT + (size_t)k * 18 + (D - 1) * 3 + q] = (float)tot / (float)L;
      }
    }
    __syncthreads();
  }
}

__global__ __launch_bounds__(256) void feat_kernel(const float* __restrict__ x,
                                                   const float* __restrict__ kern,
                                                   const float* __restrict__ ws_bias,
                                                   float* __restrict__ out, int K) {
  __shared__ __align__(16) float xs[IN_LEN + 48];  // pad for unguarded tail tap reads
  __shared__ unsigned cr[24 * 4];
  const int b = blockIdx.y, tid = threadIdx.x;

  const float4* xg = (const float4*)(x + (size_t)b * IN_LEN);
  float4* xs4 = (float4*)xs;
  for (int i = tid; i < IN_LEN / 4; i += 256) xs4[i] = xg[i];
  if (tid < 48) xs[IN_LEN + tid] = 0.f;
  const float b0 = ws_bias[0], b1 = ws_bias[1], b2 = ws_bias[2];
  __syncthreads();

  switch (blockIdx.x) {
    case 0: run_feat<1>(xs, cr, kern, b0, b1, b2, out, K, b); break;
    case 1: run_feat<2>(xs, cr, kern, b0, b1, b2, out, K, b); break;
    case 2: run_feat<3>(xs, cr, kern, b0, b1, b2, out, K, b); break;
    case 3: run_feat<4>(xs, cr, kern, b0, b1, b2, out, K, b); break;
    case 4: run_feat<5>(xs, cr, kern, b0, b1, b2, out, K, b); break;
    case 5: run_feat<6>(xs, cr, kern, b0, b1, b2, out, K, b); break;
  }
}

// ---------- kernel C: row L2 normalization over the first F columns ----------
__global__ __launch_bounds__(256) void norm_kernel(float* __restrict__ out, int F) {
  const int b = blockIdx.x, tid = threadIdx.x;
  __shared__ float red[256];
  float acc = 0.f;
  for (int i = tid; i < F; i += 256) {
    float v = out[(size_t)b * NFEAT + i];
    acc = fmaf(v, v, acc);
  }
  red[tid] = acc;
  __syncthreads();
  for (int s = 128; s > 0; s >>= 1) {
    if (tid < s) red[tid] += red[tid + s];
    __syncthreads();
  }
  const float inv = 1.0f / fmaxf(sqrtf(red[0]), 1e-12f);
  for (int i = tid; i < F; i += 256) out[(size_t)b * NFEAT + i] *= inv;
}

extern "C" void kernel_launch(void* const* d_in, const int* in_sizes, int n_in,
                              void* d_out, int out_size, void* d_ws, size_t ws_size,
                              hipStream_t stream) {
  const float* x = (const float*)d_in[0];
  const float* kern = (const float*)d_in[1];
  float* out = (float*)d_out;
  const int B = in_sizes[0] / IN_LEN;  // 256
  const int K = in_sizes[1] / 9;       // ~61 surviving kernels

  float* ws_q = (float*)d_ws;      // B*3 per-sample quantiles
  float* ws_bias = ws_q + B * 3;   // 3 biases

  // zero entire output (features overwritten; tail columns stay 0)
  hipMemsetAsync(d_out, 0, (size_t)out_size * sizeof(float), stream);

  quant_kernel<<<B, 256, 0, stream>>>(x, kern, ws_q);
  bias_kernel<<<1, 256, 0, stream>>>(ws_q, ws_bias, B);
  dim3 g(6, B);
  feat_kernel<<<g, 256, 0, stream>>>(x, kern, ws_bias, out, K);
  norm_kernel<<<B, 256, 0, stream>>>(out, K * 18);
}

// Round 3
// 276.796 us; speedup vs baseline: 1.4634x; 1.4634x over previous
//
#include <hip/hip_runtime.h>
#include <stdint.h>

#define IN_LEN 4096
#define NFEAT  10000

// ---------- sortable-key mapping for float order statistics ----------
__device__ __forceinline__ unsigned key_of(float f) {
  unsigned u = __float_as_uint(f);
  return (u & 0x80000000u) ? ~u : (u | 0x80000000u);
}
__device__ __forceinline__ float key_inv(unsigned k) {
  unsigned u = (k & 0x80000000u) ? (k ^ 0x80000000u) : ~k;
  return __uint_as_float(u);
}

// ---------- kernel A: per-sample quantiles of conv0 (kernel 0, d=1) ----------
// Each block = one sample. conv0 values (4088) live in registers (16/thread).
// Binary search in u32 key space for 6 order statistics simultaneously.
__global__ __launch_bounds__(256) void quant_kernel(const float* __restrict__ x,
                                                    const float* __restrict__ kern,
                                                    float* __restrict__ ws_q) {
  const int b = blockIdx.x, tid = threadIdx.x;
  __shared__ __align__(16) float xs[IN_LEN];
  __shared__ unsigned redc[2][6 * 4];  // double-buffered: one barrier per iter

  const float4* xg = (const float4*)(x + (size_t)b * IN_LEN);
  float4* xs4 = (float4*)xs;
  for (int i = tid; i < IN_LEN / 4; i += 256) xs4[i] = xg[i];

  float w[9];
#pragma unroll
  for (int j = 0; j < 9; j++) w[j] = kern[j];
  __syncthreads();

  const int L = IN_LEN - 8;  // 4088 valid conv positions at d=1
  unsigned keys[16];
#pragma unroll
  for (int i = 0; i < 16; i++) {
    int t = tid + (i << 8);
    if (t < L) {
      float c = 0.f;
#pragma unroll
      for (int j = 0; j < 9; j++) c = fmaf(w[j], xs[t + j], c);
      keys[i] = key_of(c);
    } else {
      keys[i] = 0xFFFFFFFFu;  // +inf pad, sorts above all real values
    }
  }

  // order-statistic indices (0-based): floor/ceil pairs for q=.25,.5,.75 of n=4088
  const int targ[6] = {1021, 1022, 2043, 2044, 3065, 3066};
  unsigned lo[6], hi[6];
#pragma unroll
  for (int q = 0; q < 6; q++) { lo[q] = 0u; hi[q] = 0xFFFFFFFFu; }

  const int wave = tid >> 6, lane = tid & 63;
  for (int it = 0; it < 32; ++it) {
    const int buf = it & 1;
    unsigned mid[6];
    int cnt[6];
#pragma unroll
    for (int q = 0; q < 6; q++) { mid[q] = lo[q] + ((hi[q] - lo[q]) >> 1); cnt[q] = 0; }
#pragma unroll
    for (int i = 0; i < 16; i++)
#pragma unroll
      for (int q = 0; q < 6; q++) cnt[q] += (keys[i] <= mid[q]) ? 1 : 0;
#pragma unroll
    for (int q = 0; q < 6; q++) {
#pragma unroll
      for (int off = 32; off > 0; off >>= 1) cnt[q] += __shfl_down(cnt[q], off);
    }
    if (lane == 0) {
#pragma unroll
      for (int q = 0; q < 6; q++) redc[buf][q * 4 + wave] = (unsigned)cnt[q];
    }
    __syncthreads();
#pragma unroll
    for (int q = 0; q < 6; q++) {
      unsigned tot = redc[buf][q * 4 + 0] + redc[buf][q * 4 + 1] +
                     redc[buf][q * 4 + 2] + redc[buf][q * 4 + 3];
      if (tot >= (unsigned)(targ[q] + 1)) hi[q] = mid[q]; else lo[q] = mid[q] + 1;
    }
    // no second barrier: next iteration uses the other redc buffer
  }

  if (tid == 0) {
    float v[6];
#pragma unroll
    for (int q = 0; q < 6; q++) v[q] = key_inv(lo[q]);
    // linear interpolation at positions 1021.75 / 2043.5 / 3065.25
    ws_q[b * 3 + 0] = v[0] + 0.75f * (v[1] - v[0]);
    ws_q[b * 3 + 1] = v[2] + 0.5f  * (v[3] - v[2]);
    ws_q[b * 3 + 2] = v[4] + 0.25f * (v[5] - v[4]);
  }
}

// ---------- kernel A2: deterministic mean over batch -> 3 biases ----------
__global__ __launch_bounds__(256) void bias_kernel(const float* __restrict__ ws_q,
                                                   float* __restrict__ ws_bias, int B) {
  __shared__ float red[256];
  const int tid = threadIdx.x;
  for (int q = 0; q < 3; q++) {
    float v = 0.f;
    for (int i = tid; i < B; i += 256) v += ws_q[i * 3 + q];
    red[tid] = v;
    __syncthreads();
    for (int s = 128; s > 0; s >>= 1) {
      if (tid < s) red[tid] += red[tid + s];
      __syncthreads();
    }
    if (tid == 0) ws_bias[q] = red[0] / (float)B;
    __syncthreads();
  }
}

// ---------- kernel B: features. One block per (dilation, sample). ----------
// Each WAVE owns a private chunk of kernels -> no barriers after staging,
// per-lane integer counters (v_cmp + v_addc), 2 positions per lane (float2).
template <int D>
__device__ __forceinline__ void run_feat(const float* xs,
                                         const float* __restrict__ kern,
                                         float b0, float b1, float b2,
                                         float* __restrict__ out, int K, int b) {
  const int tid = threadIdx.x;
  const int wave = tid >> 6, lane = tid & 63;
  constexpr int L = IN_LEN - 8 * D;
  constexpr int NFULL = 31;        // 31 full passes of 128 positions per wave
  constexpr int KT = 8;

  const int KPW = (K + 3) >> 2;    // kernels per wave (16 for K=61)
  const int kstart = wave * KPW;
  const int kend = (kstart + KPW < K) ? (kstart + KPW) : K;

  for (int k0 = kstart; k0 < kend; k0 += KT) {
    // ---- load this tile's weights (wave-uniform; clamped index keeps loads in-bounds)
    float w[KT][9];
#pragma unroll
    for (int kk = 0; kk < KT; kk++) {
      const int kidx = (k0 + kk < K) ? (k0 + kk) : (K - 1);
      const bool ok = (k0 + kk) < kend;
      const float* wp = kern + (size_t)kidx * 9;
#pragma unroll
      for (int j = 0; j < 9; j++) w[kk][j] = ok ? wp[j] : 0.f;
    }
    unsigned c0[KT], c1[KT], c2[KT];
#pragma unroll
    for (int kk = 0; kk < KT; kk++) { c0[kk] = 0u; c1[kk] = 0u; c2[kk] = 0u; }

    // ---- full passes: positions t and t+64, both always valid (max 4031 < 4048)
#pragma unroll 1
    for (int p = 0; p < NFULL; ++p) {
      const int t = (p << 7) + lane;
      float tax[9], tay[9];
#pragma unroll
      for (int j = 0; j < 9; j++) {       // pairs -> ds_read2_b32 (offsets jD, jD+64)
        tax[j] = xs[t + j * D];
        tay[j] = xs[t + 64 + j * D];
      }
#pragma unroll
      for (int kk = 0; kk < KT; kk++) {
        float ca = 0.f, cb = 0.f;
#pragma unroll
        for (int j = 0; j < 9; j++) {
          ca = fmaf(w[kk][j], tax[j], ca);
          cb = fmaf(w[kk][j], tay[j], cb);
        }
        c0[kk] += (ca > b0); c0[kk] += (cb > b0);
        c1[kk] += (ca > b1); c1[kk] += (cb > b1);
        c2[kk] += (ca > b2); c2[kk] += (cb > b2);
      }
    }
    // ---- masked tail pass: positions 3968+lane and 4032+lane
    {
      const int t = (NFULL << 7) + lane;
      const bool v0 = t < L, v1 = (t + 64) < L;
      float tax[9], tay[9];
#pragma unroll
      for (int j = 0; j < 9; j++) {       // xs padded to IN_LEN+48, always safe
        tax[j] = xs[t + j * D];
        tay[j] = xs[t + 64 + j * D];
      }
#pragma unroll
      for (int kk = 0; kk < KT; kk++) {
        float ca = 0.f, cb = 0.f;
#pragma unroll
        for (int j = 0; j < 9; j++) {
          ca = fmaf(w[kk][j], tax[j], ca);
          cb = fmaf(w[kk][j], tay[j], cb);
        }
        ca = v0 ? ca : -3.0e38f;
        cb = v1 ? cb : -3.0e38f;
        c0[kk] += (ca > b0); c0[kk] += (cb > b0);
        c1[kk] += (ca > b1); c1[kk] += (cb > b1);
        c2[kk] += (ca > b2); c2[kk] += (cb > b2);
      }
    }

    // ---- wave-level reduction: pack c0|c2 (each lane count <= 64, sum <= 4096)
#pragma unroll
    for (int kk = 0; kk < KT; kk++) {
      unsigned r0 = c0[kk] | (c2[kk] << 16);
      unsigned r1 = c1[kk];
#pragma unroll
      for (int off = 32; off > 0; off >>= 1) {
        r0 += (unsigned)__shfl_xor((int)r0, off);
        r1 += (unsigned)__shfl_xor((int)r1, off);
      }
      const int k = k0 + kk;
      if (lane == 0 && k < kend) {
        float* o = out + (size_t)b * NFEAT + (size_t)k * 18 + (D - 1) * 3;
        o[0] = (float)(r0 & 0xFFFFu) / (float)L;
        o[1] = (float)r1 / (float)L;
        o[2] = (float)(r0 >> 16) / (float)L;
      }
    }
  }
}

__global__ __launch_bounds__(256) void feat_kernel(const float* __restrict__ x,
                                                   const float* __restrict__ kern,
                                                   const float* __restrict__ ws_bias,
                                                   float* __restrict__ out, int K) {
  __shared__ __align__(16) float xs[IN_LEN + 48];  // pad for unguarded tail tap reads
  const int b = blockIdx.y, tid = threadIdx.x;

  const float4* xg = (const float4*)(x + (size_t)b * IN_LEN);
  float4* xs4 = (float4*)xs;
  for (int i = tid; i < IN_LEN / 4; i += 256) xs4[i] = xg[i];
  if (tid < 48) xs[IN_LEN + tid] = 0.f;
  const float b0 = ws_bias[0], b1 = ws_bias[1], b2 = ws_bias[2];
  __syncthreads();

  switch (blockIdx.x) {
    case 0: run_feat<1>(xs, kern, b0, b1, b2, out, K, b); break;
    case 1: run_feat<2>(xs, kern, b0, b1, b2, out, K, b); break;
    case 2: run_feat<3>(xs, kern, b0, b1, b2, out, K, b); break;
    case 3: run_feat<4>(xs, kern, b0, b1, b2, out, K, b); break;
    case 4: run_feat<5>(xs, kern, b0, b1, b2, out, K, b); break;
    case 5: run_feat<6>(xs, kern, b0, b1, b2, out, K, b); break;
  }
}

// ---------- kernel C: row L2 normalization over the first F columns ----------
__global__ __launch_bounds__(256) void norm_kernel(float* __restrict__ out, int F) {
  const int b = blockIdx.x, tid = threadIdx.x;
  __shared__ float red[256];
  float acc = 0.f;
  for (int i = tid; i < F; i += 256) {
    float v = out[(size_t)b * NFEAT + i];
    acc = fmaf(v, v, acc);
  }
  red[tid] = acc;
  __syncthreads();
  for (int s = 128; s > 0; s >>= 1) {
    if (tid < s) red[tid] += red[tid + s];
    __syncthreads();
  }
  const float inv = 1.0f / fmaxf(sqrtf(red[0]), 1e-12f);
  for (int i = tid; i < F; i += 256) out[(size_t)b * NFEAT + i] *= inv;
}

extern "C" void kernel_launch(void* const* d_in, const int* in_sizes, int n_in,
                              void* d_out, int out_size, void* d_ws, size_t ws_size,
                              hipStream_t stream) {
  const float* x = (const float*)d_in[0];
  const float* kern = (const float*)d_in[1];
  float* out = (float*)d_out;
  const int B = in_sizes[0] / IN_LEN;  // 256
  const int K = in_sizes[1] / 9;       // ~61 surviving kernels

  float* ws_q = (float*)d_ws;      // B*3 per-sample quantiles
  float* ws_bias = ws_q + B * 3;   // 3 biases

  // zero entire output (features overwritten; tail columns stay 0)
  hipMemsetAsync(d_out, 0, (size_t)out_size * sizeof(float), stream);

  quant_kernel<<<B, 256, 0, stream>>>(x, kern, ws_q);
  bias_kernel<<<1, 256, 0, stream>>>(ws_q, ws_bias, B);
  dim3 g(6, B);
  feat_kernel<<<g, 256, 0, stream>>>(x, kern, ws_bias, out, K);
  norm_kernel<<<B, 256, 0, stream>>>(out, K * 18);
}

// Round 4
// 231.182 us; speedup vs baseline: 1.7521x; 1.1973x over previous
//
#include <hip/hip_runtime.h>
#include <stdint.h>

#define IN_LEN 4096
#define NFEAT  10000

// ---------- guaranteed 2-op count-increment idioms (v_cmp + v_addc) ----------
// cnt += (val > thr)   [float]
__device__ __forceinline__ void count_gt_f32(unsigned& cnt, float thr, float val) {
  asm volatile("v_cmp_lt_f32 vcc, %1, %2\n\t"
               "v_addc_co_u32 %0, vcc, 0, %0, vcc"
               : "+v"(cnt)
               : "v"(thr), "v"(val)
               : "vcc");
}
// cnt += (key <= mid)  [unsigned]
__device__ __forceinline__ void count_le_u32(unsigned& cnt, unsigned mid, unsigned key) {
  asm volatile("v_cmp_ge_u32 vcc, %1, %2\n\t"
               "v_addc_co_u32 %0, vcc, 0, %0, vcc"
               : "+v"(cnt)
               : "v"(mid), "v"(key)
               : "vcc");
}

// ---------- sortable-key mapping for float order statistics ----------
__device__ __forceinline__ unsigned key_of(float f) {
  unsigned u = __float_as_uint(f);
  return (u & 0x80000000u) ? ~u : (u | 0x80000000u);
}
__device__ __forceinline__ float key_inv(unsigned k) {
  unsigned u = (k & 0x80000000u) ? (k ^ 0x80000000u) : ~k;
  return __uint_as_float(u);
}

// ---------- kernel A: per-sample quantiles of conv0 (kernel 0, d=1) ----------
// Each block = one sample. conv0 values (4088) live in registers (16/thread).
// Binary search in u32 key space for 6 order statistics simultaneously.
__global__ __launch_bounds__(256) void quant_kernel(const float* __restrict__ x,
                                                    const float* __restrict__ kern,
                                                    float* __restrict__ ws_q) {
  const int b = blockIdx.x, tid = threadIdx.x;
  __shared__ __align__(16) float xs[IN_LEN];
  __shared__ unsigned redc[2][3 * 4];  // 3 packed counters x 4 waves, double-buffered

  const float4* xg = (const float4*)(x + (size_t)b * IN_LEN);
  float4* xs4 = (float4*)xs;
  for (int i = tid; i < IN_LEN / 4; i += 256) xs4[i] = xg[i];

  float w[9];
#pragma unroll
  for (int j = 0; j < 9; j++) w[j] = kern[j];
  __syncthreads();

  const int L = IN_LEN - 8;  // 4088 valid conv positions at d=1
  unsigned keys[16];
#pragma unroll
  for (int i = 0; i < 16; i++) {
    int t = tid + (i << 8);
    if (t < L) {
      float c = 0.f;
#pragma unroll
      for (int j = 0; j < 9; j++) c = fmaf(w[j], xs[t + j], c);
      keys[i] = key_of(c);
    } else {
      keys[i] = 0xFFFFFFFFu;  // +inf pad, sorts above all real values
    }
  }

  // order-statistic indices (0-based): floor/ceil pairs for q=.25,.5,.75 of n=4088
  const int targ[6] = {1021, 1022, 2043, 2044, 3065, 3066};
  unsigned lo[6], hi[6];
#pragma unroll
  for (int q = 0; q < 6; q++) { lo[q] = 0u; hi[q] = 0xFFFFFFFFu; }

  const int wave = tid >> 6, lane = tid & 63;
  for (int it = 0; it < 32; ++it) {
    const int buf = it & 1;
    unsigned mid[6], cnt[6];
#pragma unroll
    for (int q = 0; q < 6; q++) { mid[q] = lo[q] + ((hi[q] - lo[q]) >> 1); cnt[q] = 0u; }
#pragma unroll
    for (int i = 0; i < 16; i++)
#pragma unroll
      for (int q = 0; q < 6; q++) count_le_u32(cnt[q], mid[q], keys[i]);
    // pack pairs (wave sums <= 1024 fit 16 bits) -> 3 shuffle chains instead of 6
    unsigned r[3];
#pragma unroll
    for (int q = 0; q < 3; q++) r[q] = cnt[2 * q] | (cnt[2 * q + 1] << 16);
#pragma unroll
    for (int q = 0; q < 3; q++) {
#pragma unroll
      for (int off = 32; off > 0; off >>= 1) r[q] += (unsigned)__shfl_xor((int)r[q], off);
    }
    if (lane == 0) {
#pragma unroll
      for (int q = 0; q < 3; q++) redc[buf][q * 4 + wave] = r[q];
    }
    __syncthreads();
#pragma unroll
    for (int q = 0; q < 3; q++) {
      unsigned tot = redc[buf][q * 4 + 0] + redc[buf][q * 4 + 1] +
                     redc[buf][q * 4 + 2] + redc[buf][q * 4 + 3];
      unsigned t0 = tot & 0xFFFFu, t1 = tot >> 16;
      if (t0 >= (unsigned)(targ[2 * q] + 1)) hi[2 * q] = mid[2 * q]; else lo[2 * q] = mid[2 * q] + 1;
      if (t1 >= (unsigned)(targ[2 * q + 1] + 1)) hi[2 * q + 1] = mid[2 * q + 1]; else lo[2 * q + 1] = mid[2 * q + 1] + 1;
    }
    // no second barrier: next iteration uses the other redc buffer
  }

  if (tid == 0) {
    float v[6];
#pragma unroll
    for (int q = 0; q < 6; q++) v[q] = key_inv(lo[q]);
    // linear interpolation at positions 1021.75 / 2043.5 / 3065.25
    ws_q[b * 3 + 0] = v[0] + 0.75f * (v[1] - v[0]);
    ws_q[b * 3 + 1] = v[2] + 0.5f  * (v[3] - v[2]);
    ws_q[b * 3 + 2] = v[4] + 0.25f * (v[5] - v[4]);
  }
}

// ---------- kernel A2: deterministic mean over batch -> 3 biases ----------
__global__ __launch_bounds__(256) void bias_kernel(const float* __restrict__ ws_q,
                                                   float* __restrict__ ws_bias, int B) {
  __shared__ float red[256];
  const int tid = threadIdx.x;
  for (int q = 0; q < 3; q++) {
    float v = 0.f;
    for (int i = tid; i < B; i += 256) v += ws_q[i * 3 + q];
    red[tid] = v;
    __syncthreads();
    for (int s = 128; s > 0; s >>= 1) {
      if (tid < s) red[tid] += red[tid + s];
      __syncthreads();
    }
    if (tid == 0) ws_bias[q] = red[0] / (float)B;
    __syncthreads();
  }
}

// ---------- kernel B: features. One block per (dilation, sample). ----------
// Each WAVE owns a private chunk of kernels -> no barriers after staging,
// per-lane counters via v_cmp+v_addc (2 VALU), 2 positions per lane.
template <int D>
__device__ __forceinline__ void run_feat(const float* xs,
                                         const float* __restrict__ kern,
                                         float b0, float b1, float b2,
                                         float* __restrict__ out, int K, int b) {
  const int tid = threadIdx.x;
  const int wave = tid >> 6, lane = tid & 63;
  constexpr int L = IN_LEN - 8 * D;
  constexpr int NFULL = 31;        // 31 full passes of 128 positions per wave
  constexpr int KT = 8;

  const int KPW = (K + 3) >> 2;    // kernels per wave (16 for K=61)
  const int kstart = wave * KPW;
  const int kend = (kstart + KPW < K) ? (kstart + KPW) : K;

  for (int k0 = kstart; k0 < kend; k0 += KT) {
    // ---- load this tile's weights (wave-uniform; clamped index keeps loads in-bounds)
    float w[KT][9];
#pragma unroll
    for (int kk = 0; kk < KT; kk++) {
      const int kidx = (k0 + kk < K) ? (k0 + kk) : (K - 1);
      const bool ok = (k0 + kk) < kend;
      const float* wp = kern + (size_t)kidx * 9;
#pragma unroll
      for (int j = 0; j < 9; j++) w[kk][j] = ok ? wp[j] : 0.f;
    }
    unsigned c0[KT], c1[KT], c2[KT];
#pragma unroll
    for (int kk = 0; kk < KT; kk++) { c0[kk] = 0u; c1[kk] = 0u; c2[kk] = 0u; }

    // ---- full passes: positions t and t+64, both always valid (max 4031 < 4048)
#pragma unroll 1
    for (int p = 0; p < NFULL; ++p) {
      const int t = (p << 7) + lane;
      float tax[9], tay[9];
#pragma unroll
      for (int j = 0; j < 9; j++) {       // pairs -> ds_read2_b32 (offsets jD, jD+64)
        tax[j] = xs[t + j * D];
        tay[j] = xs[t + 64 + j * D];
      }
#pragma unroll
      for (int kk = 0; kk < KT; kk++) {
        float ca = 0.f, cb = 0.f;
#pragma unroll
        for (int j = 0; j < 9; j++) {
          ca = fmaf(w[kk][j], tax[j], ca);
          cb = fmaf(w[kk][j], tay[j], cb);
        }
        count_gt_f32(c0[kk], b0, ca); count_gt_f32(c0[kk], b0, cb);
        count_gt_f32(c1[kk], b1, ca); count_gt_f32(c1[kk], b1, cb);
        count_gt_f32(c2[kk], b2, ca); count_gt_f32(c2[kk], b2, cb);
      }
    }
    // ---- masked tail pass: positions 3968+lane and 4032+lane
    {
      const int t = (NFULL << 7) + lane;
      const bool v0 = t < L, v1 = (t + 64) < L;
      float tax[9], tay[9];
#pragma unroll
      for (int j = 0; j < 9; j++) {       // xs padded to IN_LEN+48, always safe
        tax[j] = xs[t + j * D];
        tay[j] = xs[t + 64 + j * D];
      }
#pragma unroll
      for (int kk = 0; kk < KT; kk++) {
        float ca = 0.f, cb = 0.f;
#pragma unroll
        for (int j = 0; j < 9; j++) {
          ca = fmaf(w[kk][j], tax[j], ca);
          cb = fmaf(w[kk][j], tay[j], cb);
        }
        ca = v0 ? ca : -3.0e38f;   // thresholds are O(1): always > -3e38
        cb = v1 ? cb : -3.0e38f;
        count_gt_f32(c0[kk], b0, ca); count_gt_f32(c0[kk], b0, cb);
        count_gt_f32(c1[kk], b1, ca); count_gt_f32(c1[kk], b1, cb);
        count_gt_f32(c2[kk], b2, ca); count_gt_f32(c2[kk], b2, cb);
      }
    }

    // ---- wave-level reduction: pack c0|c2 (lane count <= 64, wave sum <= 4096)
#pragma unroll
    for (int kk = 0; kk < KT; kk++) {
      unsigned r0 = c0[kk] | (c2[kk] << 16);
      unsigned r1 = c1[kk];
#pragma unroll
      for (int off = 32; off > 0; off >>= 1) {
        r0 += (unsigned)__shfl_xor((int)r0, off);
        r1 += (unsigned)__shfl_xor((int)r1, off);
      }
      const int k = k0 + kk;
      if (lane == 0 && k < kend) {
        float* o = out + (size_t)b * NFEAT + (size_t)k * 18 + (D - 1) * 3;
        o[0] = (float)(r0 & 0xFFFFu) / (float)L;
        o[1] = (float)r1 / (float)L;
        o[2] = (float)(r0 >> 16) / (float)L;
      }
    }
  }
}

__global__ __launch_bounds__(256) void feat_kernel(const float* __restrict__ x,
                                                   const float* __restrict__ kern,
                                                   const float* __restrict__ ws_bias,
                                                   float* __restrict__ out, int K) {
  __shared__ __align__(16) float xs[IN_LEN + 48];  // pad for unguarded tail tap reads
  const int b = blockIdx.y, tid = threadIdx.x;

  const float4* xg = (const float4*)(x + (size_t)b * IN_LEN);
  float4* xs4 = (float4*)xs;
  for (int i = tid; i < IN_LEN / 4; i += 256) xs4[i] = xg[i];
  if (tid < 48) xs[IN_LEN + tid] = 0.f;
  const float b0 = ws_bias[0], b1 = ws_bias[1], b2 = ws_bias[2];
  __syncthreads();

  switch (blockIdx.x) {
    case 0: run_feat<1>(xs, kern, b0, b1, b2, out, K, b); break;
    case 1: run_feat<2>(xs, kern, b0, b1, b2, out, K, b); break;
    case 2: run_feat<3>(xs, kern, b0, b1, b2, out, K, b); break;
    case 3: run_feat<4>(xs, kern, b0, b1, b2, out, K, b); break;
    case 4: run_feat<5>(xs, kern, b0, b1, b2, out, K, b); break;
    case 5: run_feat<6>(xs, kern, b0, b1, b2, out, K, b); break;
  }
}

// ---------- kernel C: row L2 normalization over the first F columns ----------
__global__ __launch_bounds__(256) void norm_kernel(float* __restrict__ out, int F) {
  const int b = blockIdx.x, tid = threadIdx.x;
  __shared__ float red[256];
  float acc = 0.f;
  for (int i = tid; i < F; i += 256) {
    float v = out[(size_t)b * NFEAT + i];
    acc = fmaf(v, v, acc);
  }
  red[tid] = acc;
  __syncthreads();
  for (int s = 128; s > 0; s >>= 1) {
    if (tid < s) red[tid] += red[tid + s];
    __syncthreads();
  }
  const float inv = 1.0f / fmaxf(sqrtf(red[0]), 1e-12f);
  for (int i = tid; i < F; i += 256) out[(size_t)b * NFEAT + i] *= inv;
}

extern "C" void kernel_launch(void* const* d_in, const int* in_sizes, int n_in,
                              void* d_out, int out_size, void* d_ws, size_t ws_size,
                              hipStream_t stream) {
  const float* x = (const float*)d_in[0];
  const float* kern = (const float*)d_in[1];
  float* out = (float*)d_out;
  const int B = in_sizes[0] / IN_LEN;  // 256
  const int K = in_sizes[1] / 9;       // ~61 surviving kernels

  float* ws_q = (float*)d_ws;      // B*3 per-sample quantiles
  float* ws_bias = ws_q + B * 3;   // 3 biases

  // zero entire output (features overwritten; tail columns stay 0)
  hipMemsetAsync(d_out, 0, (size_t)out_size * sizeof(float), stream);

  quant_kernel<<<B, 256, 0, stream>>>(x, kern, ws_q);
  bias_kernel<<<1, 256, 0, stream>>>(ws_q, ws_bias, B);
  dim3 g(6, B);
  feat_kernel<<<g, 256, 0, stream>>>(x, kern, ws_bias, out, K);
  norm_kernel<<<B, 256, 0, stream>>>(out, K * 18);
}